// Round 1
// baseline (427.858 us; speedup 1.0000x reference)
//
#include <hip/hip_runtime.h>
#include <hip/hip_bf16.h>

#define NN 50000
#define NE 625000
#define D 128

// ---------------- CSR build ----------------

__global__ void count_kernel(const int* __restrict__ col, int* __restrict__ counts) {
    int i = blockIdx.x * blockDim.x + threadIdx.x;
    if (i < NE) atomicAdd(&counts[col[i]], 1);
}

__global__ __launch_bounds__(1024) void scan_kernel(const int* __restrict__ counts,
                                                    int* __restrict__ offsets,
                                                    int* __restrict__ cursor,
                                                    float* __restrict__ dinv) {
    __shared__ int sdata[1024];
    __shared__ int s_carry;
    const int t = threadIdx.x;
    if (t == 0) s_carry = 0;
    __syncthreads();
    for (int base = 0; base < NN; base += 1024) {
        int i = base + t;
        int v = (i < NN) ? counts[i] : 0;
        sdata[t] = v;
        __syncthreads();
        for (int off = 1; off < 1024; off <<= 1) {
            int add = (t >= off) ? sdata[t - off] : 0;
            __syncthreads();
            sdata[t] += add;
            __syncthreads();
        }
        int incl = sdata[t];
        int carry = s_carry;
        __syncthreads();  // everyone reads s_carry before t=1023 updates it
        if (i < NN) {
            int excl = carry + incl - v;
            offsets[i] = excl;
            cursor[i] = excl;
            dinv[i] = rsqrtf((float)v + 1.0f);  // deg includes self-loop
        }
        if (t == 1023) s_carry = carry + incl;
        __syncthreads();
    }
    if (t == 0) offsets[NN] = s_carry;
}

__global__ void fill_kernel(const int* __restrict__ row, const int* __restrict__ col,
                            int* __restrict__ cursor, int* __restrict__ csr_src) {
    int i = blockIdx.x * blockDim.x + threadIdx.x;
    if (i < NE) {
        int c = col[i];
        int p = atomicAdd(&cursor[c], 1);
        csr_src[p] = row[i];
    }
}

// ---------------- dense GEMM: H = A @ W  (fp32 VALU) ----------------
// Block: 128 rows x 128 cols, 256 threads, 8x8 register tile each.
// LDS: W full (64KB) + A tile row-major padded stride 132 (67.6KB) = 130KB.

__global__ __launch_bounds__(256) void gemm_kernel(const float* __restrict__ A,
                                                   const float* __restrict__ W,
                                                   float* __restrict__ H) {
    __shared__ float As[128 * 132];  // [r][k], padded
    __shared__ float Ws[128 * 128];  // [k][j]
    const int t = threadIdx.x;
    const int row0 = blockIdx.x * 128;

    const float4* W4 = (const float4*)W;
    float4* Ws4 = (float4*)Ws;
    #pragma unroll 4
    for (int i = t; i < 4096; i += 256) Ws4[i] = W4[i];

    float4* As4 = (float4*)As;  // row stride = 33 float4
    for (int i = t; i < 4096; i += 256) {
        int r = i >> 5, kq = i & 31;
        int gr = row0 + r;
        if (gr >= NN) gr = NN - 1;  // clamp; stores are guarded
        As4[r * 33 + kq] = *(const float4*)(A + (size_t)gr * D + kq * 4);
    }
    __syncthreads();

    const int rg = t >> 4;  // 0..15 -> rows 8*rg..
    const int jc = t & 15;  // 0..15 -> cols 8*jc..
    float acc[8][8];
    #pragma unroll
    for (int m = 0; m < 8; m++)
        #pragma unroll
        for (int c = 0; c < 8; c++) acc[m][c] = 0.0f;

    for (int k4 = 0; k4 < 32; k4++) {
        float4 a[8];
        #pragma unroll
        for (int m = 0; m < 8; m++) a[m] = As4[(8 * rg + m) * 33 + k4];
        #pragma unroll
        for (int kk = 0; kk < 4; kk++) {
            int k = 4 * k4 + kk;
            float4 w0 = Ws4[k * 32 + jc * 2];
            float4 w1 = Ws4[k * 32 + jc * 2 + 1];
            #pragma unroll
            for (int m = 0; m < 8; m++) {
                float av = (kk == 0) ? a[m].x : (kk == 1) ? a[m].y
                         : (kk == 2) ? a[m].z : a[m].w;
                acc[m][0] += av * w0.x;
                acc[m][1] += av * w0.y;
                acc[m][2] += av * w0.z;
                acc[m][3] += av * w0.w;
                acc[m][4] += av * w1.x;
                acc[m][5] += av * w1.y;
                acc[m][6] += av * w1.z;
                acc[m][7] += av * w1.w;
            }
        }
    }

    #pragma unroll
    for (int m = 0; m < 8; m++) {
        int gr = row0 + 8 * rg + m;
        if (gr < NN) {
            float4* Hp = (float4*)(H + (size_t)gr * D + jc * 8);
            Hp[0] = make_float4(acc[m][0], acc[m][1], acc[m][2], acc[m][3]);
            Hp[1] = make_float4(acc[m][4], acc[m][5], acc[m][6], acc[m][7]);
        }
    }
}

// ---------------- aggregation: out[i] = sum_e norm*h[src] + dinv[i]^2*h[i] + b ----------------
// One 128-thread block per node; coalesced 512B gathers of h rows.

__global__ __launch_bounds__(128) void agg_kernel(const float* __restrict__ h,
                                                  const int* __restrict__ offsets,
                                                  const int* __restrict__ csr_src,
                                                  const float* __restrict__ dinv,
                                                  const float* __restrict__ bias,
                                                  float* __restrict__ out,
                                                  const int relu) {
    const int i = blockIdx.x;
    const int t = threadIdx.x;
    const float di = dinv[i];
    float acc = di * di * h[(size_t)i * D + t];
    const int e0 = offsets[i];
    const int e1 = offsets[i + 1];
    int e = e0;
    for (; e + 4 <= e1; e += 4) {
        int s0 = csr_src[e + 0];
        int s1 = csr_src[e + 1];
        int s2 = csr_src[e + 2];
        int s3 = csr_src[e + 3];
        float w0 = dinv[s0] * di;
        float w1 = dinv[s1] * di;
        float w2 = dinv[s2] * di;
        float w3 = dinv[s3] * di;
        float v0 = h[(size_t)s0 * D + t];
        float v1 = h[(size_t)s1 * D + t];
        float v2 = h[(size_t)s2 * D + t];
        float v3 = h[(size_t)s3 * D + t];
        acc += w0 * v0;
        acc += w1 * v1;
        acc += w2 * v2;
        acc += w3 * v3;
    }
    for (; e < e1; e++) {
        int s = csr_src[e];
        acc += dinv[s] * di * h[(size_t)s * D + t];
    }
    float v = acc + bias[t];
    if (relu) v = fmaxf(v, 0.0f);
    out[(size_t)i * D + t] = v;
}

// ---------------- launch ----------------

extern "C" void kernel_launch(void* const* d_in, const int* in_sizes, int n_in,
                              void* d_out, int out_size, void* d_ws, size_t ws_size,
                              hipStream_t stream) {
    (void)in_sizes; (void)n_in; (void)out_size; (void)ws_size;
    const float* x  = (const float*)d_in[0];
    const int*   ei = (const int*)d_in[1];
    const float* W1 = (const float*)d_in[2];
    const float* b1 = (const float*)d_in[3];
    const float* W2 = (const float*)d_in[4];
    const float* b2 = (const float*)d_in[5];
    const float* W3 = (const float*)d_in[6];
    const float* b3 = (const float*)d_in[7];
    const int* row = ei;
    const int* col = ei + NE;
    float* outp = (float*)d_out;

    char* ws = (char*)d_ws;
    size_t off = 0;
    auto walloc = [&](size_t bytes) -> void* {
        void* p = ws + off;
        off = (off + bytes + 255) & ~(size_t)255;
        return p;
    };
    int*   counts  = (int*)walloc(NN * 4);
    int*   offsets = (int*)walloc((NN + 1) * 4);
    int*   cursor  = (int*)walloc(NN * 4);
    float* dinv    = (float*)walloc(NN * 4);
    int*   csr_src = (int*)walloc((size_t)NE * 4);
    float* hbuf    = (float*)walloc((size_t)NN * D * 4);
    float* act     = (float*)walloc((size_t)NN * D * 4);

    hipMemsetAsync(counts, 0, NN * 4, stream);
    count_kernel<<<(NE + 255) / 256, 256, 0, stream>>>(col, counts);
    scan_kernel<<<1, 1024, 0, stream>>>(counts, offsets, cursor, dinv);
    fill_kernel<<<(NE + 255) / 256, 256, 0, stream>>>(row, col, cursor, csr_src);

    const int gblocks = (NN + 127) / 128;
    // layer 1
    gemm_kernel<<<gblocks, 256, 0, stream>>>(x, W1, hbuf);
    agg_kernel<<<NN, 128, 0, stream>>>(hbuf, offsets, csr_src, dinv, b1, act, 1);
    // layer 2
    gemm_kernel<<<gblocks, 256, 0, stream>>>(act, W2, hbuf);
    agg_kernel<<<NN, 128, 0, stream>>>(hbuf, offsets, csr_src, dinv, b2, act, 1);
    // layer 3 (no relu)
    gemm_kernel<<<gblocks, 256, 0, stream>>>(act, W3, hbuf);
    agg_kernel<<<NN, 128, 0, stream>>>(hbuf, offsets, csr_src, dinv, b3, outp, 0);
}

// Round 2
// 343.283 us; speedup vs baseline: 1.2464x; 1.2464x over previous
//
#include <hip/hip_runtime.h>
#include <hip/hip_bf16.h>

#define NN 50000
#define NE 625000
#define D 128
#define SCAN_BLK 1024  // elements per scan1 block
#define NSB ((NN + SCAN_BLK - 1) / SCAN_BLK)  // 49

// ---------------- CSR build ----------------

__global__ void count_kernel(const int* __restrict__ col, int* __restrict__ counts) {
    int i = blockIdx.x * blockDim.x + threadIdx.x;
    if (i < NE) atomicAdd(&counts[col[i]], 1);
}

// 256 threads x 4 elements = 1024 counts per block; wave-shuffle scan.
__global__ __launch_bounds__(256) void scan1_kernel(const int* __restrict__ counts,
                                                    int* __restrict__ excl,
                                                    int* __restrict__ blocksums) {
    const int b = blockIdx.x, t = threadIdx.x;
    const int base = b * SCAN_BLK + t * 4;
    int v0 = 0, v1 = 0, v2 = 0, v3 = 0;
    if (base + 3 < NN) {
        int4 c = *(const int4*)(counts + base);
        v0 = c.x; v1 = c.y; v2 = c.z; v3 = c.w;
    } else {
        if (base     < NN) v0 = counts[base];
        if (base + 1 < NN) v1 = counts[base + 1];
        if (base + 2 < NN) v2 = counts[base + 2];
        if (base + 3 < NN) v3 = counts[base + 3];
    }
    const int s = v0 + v1 + v2 + v3;
    const int lane = t & 63, wid = t >> 6;
    int inc = s;
    #pragma unroll
    for (int off = 1; off < 64; off <<= 1) {
        int n = __shfl_up(inc, off, 64);
        if (lane >= off) inc += n;
    }
    __shared__ int wsum[4];
    if (lane == 63) wsum[wid] = inc;
    __syncthreads();
    int wbase = 0;
    for (int w = 0; w < wid; w++) wbase += wsum[w];
    const int texcl = wbase + inc - s;
    if (base     < NN) excl[base]     = texcl;
    if (base + 1 < NN) excl[base + 1] = texcl + v0;
    if (base + 2 < NN) excl[base + 2] = texcl + v0 + v1;
    if (base + 3 < NN) excl[base + 3] = texcl + v0 + v1 + v2;
    if (t == 255) blocksums[b] = wbase + inc;
}

__global__ __launch_bounds__(64) void scan2_kernel(const int* __restrict__ blocksums,
                                                   int* __restrict__ blockoff) {
    const int t = threadIdx.x;
    int v = (t < NSB) ? blocksums[t] : 0;
    int inc = v;
    #pragma unroll
    for (int off = 1; off < 64; off <<= 1) {
        int n = __shfl_up(inc, off, 64);
        if (t >= off) inc += n;
    }
    if (t < NSB) blockoff[t] = inc - v;
}

__global__ void scan3_kernel(const int* __restrict__ counts, const int* __restrict__ excl,
                             const int* __restrict__ blockoff, int* __restrict__ offsets,
                             int* __restrict__ cursor, float* __restrict__ dinv) {
    const int i = blockIdx.x * blockDim.x + threadIdx.x;
    if (i < NN) {
        const int o = excl[i] + blockoff[i >> 10];
        offsets[i] = o;
        cursor[i] = o;
        dinv[i] = rsqrtf((float)counts[i] + 1.0f);  // deg includes self-loop
    }
    if (i == 0) offsets[NN] = NE;
}

__global__ void fill_kernel(const int* __restrict__ row, const int* __restrict__ col,
                            const float* __restrict__ dinv, int* __restrict__ cursor,
                            int* __restrict__ csr_src, float* __restrict__ csr_w) {
    int i = blockIdx.x * blockDim.x + threadIdx.x;
    if (i < NE) {
        int r = row[i], c = col[i];
        int p = atomicAdd(&cursor[c], 1);
        csr_src[p] = r;
        csr_w[p] = dinv[r] * dinv[c];
    }
}

// ---------------- dense GEMM: H = A @ W  (fp32 VALU) ----------------

__global__ __launch_bounds__(256) void gemm_kernel(const float* __restrict__ A,
                                                   const float* __restrict__ W,
                                                   float* __restrict__ H) {
    __shared__ float As[128 * 132];  // [r][k], padded
    __shared__ float Ws[128 * 128];  // [k][j]
    const int t = threadIdx.x;
    const int row0 = blockIdx.x * 128;

    const float4* W4 = (const float4*)W;
    float4* Ws4 = (float4*)Ws;
    #pragma unroll 4
    for (int i = t; i < 4096; i += 256) Ws4[i] = W4[i];

    float4* As4 = (float4*)As;  // row stride = 33 float4
    for (int i = t; i < 4096; i += 256) {
        int r = i >> 5, kq = i & 31;
        int gr = row0 + r;
        if (gr >= NN) gr = NN - 1;  // clamp; stores are guarded
        As4[r * 33 + kq] = *(const float4*)(A + (size_t)gr * D + kq * 4);
    }
    __syncthreads();

    const int rg = t >> 4;
    const int jc = t & 15;
    float acc[8][8];
    #pragma unroll
    for (int m = 0; m < 8; m++)
        #pragma unroll
        for (int c = 0; c < 8; c++) acc[m][c] = 0.0f;

    for (int k4 = 0; k4 < 32; k4++) {
        float4 a[8];
        #pragma unroll
        for (int m = 0; m < 8; m++) a[m] = As4[(8 * rg + m) * 33 + k4];
        #pragma unroll
        for (int kk = 0; kk < 4; kk++) {
            int k = 4 * k4 + kk;
            float4 w0 = Ws4[k * 32 + jc * 2];
            float4 w1 = Ws4[k * 32 + jc * 2 + 1];
            #pragma unroll
            for (int m = 0; m < 8; m++) {
                float av = (kk == 0) ? a[m].x : (kk == 1) ? a[m].y
                         : (kk == 2) ? a[m].z : a[m].w;
                acc[m][0] += av * w0.x;
                acc[m][1] += av * w0.y;
                acc[m][2] += av * w0.z;
                acc[m][3] += av * w0.w;
                acc[m][4] += av * w1.x;
                acc[m][5] += av * w1.y;
                acc[m][6] += av * w1.z;
                acc[m][7] += av * w1.w;
            }
        }
    }

    #pragma unroll
    for (int m = 0; m < 8; m++) {
        int gr = row0 + 8 * rg + m;
        if (gr < NN) {
            float4* Hp = (float4*)(H + (size_t)gr * D + jc * 8);
            Hp[0] = make_float4(acc[m][0], acc[m][1], acc[m][2], acc[m][3]);
            Hp[1] = make_float4(acc[m][4], acc[m][5], acc[m][6], acc[m][7]);
        }
    }
}

// ---------------- aggregation ----------------
// out[i] = sum_e w[e]*h[src[e]] + dinv[i]^2*h[i] + b ; 32 lanes x float4 per node,
// 8 nodes per 256-thread block, 2-way unrolled dual accumulators.

__global__ __launch_bounds__(256) void agg_kernel(const float* __restrict__ h,
                                                  const int* __restrict__ offsets,
                                                  const int* __restrict__ csr_src,
                                                  const float* __restrict__ csr_w,
                                                  const float* __restrict__ dinv,
                                                  const float* __restrict__ bias,
                                                  float* __restrict__ out,
                                                  const int relu) {
    const int node = blockIdx.x * 8 + (threadIdx.x >> 5);
    const int l = threadIdx.x & 31;
    if (node >= NN) return;
    const float di = dinv[node];
    const float sw = di * di;
    float4 hv = *(const float4*)(h + (size_t)node * D + l * 4);
    float4 acc0 = make_float4(sw * hv.x, sw * hv.y, sw * hv.z, sw * hv.w);
    float4 acc1 = make_float4(0.f, 0.f, 0.f, 0.f);
    const int e0 = offsets[node];
    const int e1 = offsets[node + 1];
    int e = e0;
    for (; e + 2 <= e1; e += 2) {
        int s0 = csr_src[e];
        int s1 = csr_src[e + 1];
        float w0 = csr_w[e];
        float w1 = csr_w[e + 1];
        float4 v0 = *(const float4*)(h + (size_t)s0 * D + l * 4);
        float4 v1 = *(const float4*)(h + (size_t)s1 * D + l * 4);
        acc0.x += w0 * v0.x; acc0.y += w0 * v0.y; acc0.z += w0 * v0.z; acc0.w += w0 * v0.w;
        acc1.x += w1 * v1.x; acc1.y += w1 * v1.y; acc1.z += w1 * v1.z; acc1.w += w1 * v1.w;
    }
    if (e < e1) {
        int s = csr_src[e];
        float w = csr_w[e];
        float4 v = *(const float4*)(h + (size_t)s * D + l * 4);
        acc0.x += w * v.x; acc0.y += w * v.y; acc0.z += w * v.z; acc0.w += w * v.w;
    }
    float4 bv = *(const float4*)(bias + l * 4);
    float4 r;
    r.x = acc0.x + acc1.x + bv.x;
    r.y = acc0.y + acc1.y + bv.y;
    r.z = acc0.z + acc1.z + bv.z;
    r.w = acc0.w + acc1.w + bv.w;
    if (relu) {
        r.x = fmaxf(r.x, 0.f); r.y = fmaxf(r.y, 0.f);
        r.z = fmaxf(r.z, 0.f); r.w = fmaxf(r.w, 0.f);
    }
    *(float4*)(out + (size_t)node * D + l * 4) = r;
}

// ---------------- launch ----------------

extern "C" void kernel_launch(void* const* d_in, const int* in_sizes, int n_in,
                              void* d_out, int out_size, void* d_ws, size_t ws_size,
                              hipStream_t stream) {
    (void)in_sizes; (void)n_in; (void)out_size; (void)ws_size;
    const float* x  = (const float*)d_in[0];
    const int*   ei = (const int*)d_in[1];
    const float* W1 = (const float*)d_in[2];
    const float* b1 = (const float*)d_in[3];
    const float* W2 = (const float*)d_in[4];
    const float* b2 = (const float*)d_in[5];
    const float* W3 = (const float*)d_in[6];
    const float* b3 = (const float*)d_in[7];
    const int* row = ei;
    const int* col = ei + NE;
    float* outp = (float*)d_out;

    char* ws = (char*)d_ws;
    size_t off = 0;
    auto walloc = [&](size_t bytes) -> void* {
        void* p = ws + off;
        off = (off + bytes + 255) & ~(size_t)255;
        return p;
    };
    int*   counts   = (int*)walloc(NN * 4);
    int*   excl     = (int*)walloc(NN * 4);
    int*   blocksums= (int*)walloc(NSB * 4);
    int*   blockoff = (int*)walloc(NSB * 4);
    int*   offsets  = (int*)walloc((NN + 1) * 4);
    int*   cursor   = (int*)walloc(NN * 4);
    float* dinv     = (float*)walloc(NN * 4);
    int*   csr_src  = (int*)walloc((size_t)NE * 4);
    float* csr_w    = (float*)walloc((size_t)NE * 4);
    float* hbuf     = (float*)walloc((size_t)NN * D * 4);
    float* act      = (float*)walloc((size_t)NN * D * 4);

    hipMemsetAsync(counts, 0, NN * 4, stream);
    count_kernel<<<(NE + 255) / 256, 256, 0, stream>>>(col, counts);
    scan1_kernel<<<NSB, 256, 0, stream>>>(counts, excl, blocksums);
    scan2_kernel<<<1, 64, 0, stream>>>(blocksums, blockoff);
    scan3_kernel<<<(NN + 255) / 256, 256, 0, stream>>>(counts, excl, blockoff,
                                                       offsets, cursor, dinv);
    fill_kernel<<<(NE + 255) / 256, 256, 0, stream>>>(row, col, dinv, cursor,
                                                      csr_src, csr_w);

    const int gblocks = (NN + 127) / 128;
    // layer 1
    gemm_kernel<<<gblocks, 256, 0, stream>>>(x, W1, hbuf);
    agg_kernel<<<(NN + 7) / 8, 256, 0, stream>>>(hbuf, offsets, csr_src, csr_w, dinv, b1, act, 1);
    // layer 2
    gemm_kernel<<<gblocks, 256, 0, stream>>>(act, W2, hbuf);
    agg_kernel<<<(NN + 7) / 8, 256, 0, stream>>>(hbuf, offsets, csr_src, csr_w, dinv, b2, act, 1);
    // layer 3 (no relu)
    gemm_kernel<<<gblocks, 256, 0, stream>>>(act, W3, hbuf);
    agg_kernel<<<(NN + 7) / 8, 256, 0, stream>>>(hbuf, offsets, csr_src, csr_w, dinv, b3, outp, 0);
}

// Round 3
// 317.294 us; speedup vs baseline: 1.3485x; 1.0819x over previous
//
#include <hip/hip_runtime.h>
#include <hip/hip_bf16.h>

#define NN 50000
#define NE 625000
#define D 128
#define SCAN_BLK 1024  // elements per scan1 block
#define NSB ((NN + SCAN_BLK - 1) / SCAN_BLK)  // 49

// ---------------- CSR build ----------------

__global__ void count_kernel(const int* __restrict__ col, int* __restrict__ counts) {
    int i = blockIdx.x * blockDim.x + threadIdx.x;
    if (i < NE) atomicAdd(&counts[col[i]], 1);
}

// 256 threads x 4 elements = 1024 counts per block; wave-shuffle scan.
__global__ __launch_bounds__(256) void scan1_kernel(const int* __restrict__ counts,
                                                    int* __restrict__ excl,
                                                    int* __restrict__ blocksums) {
    const int b = blockIdx.x, t = threadIdx.x;
    const int base = b * SCAN_BLK + t * 4;
    int v0 = 0, v1 = 0, v2 = 0, v3 = 0;
    if (base + 3 < NN) {
        int4 c = *(const int4*)(counts + base);
        v0 = c.x; v1 = c.y; v2 = c.z; v3 = c.w;
    } else {
        if (base     < NN) v0 = counts[base];
        if (base + 1 < NN) v1 = counts[base + 1];
        if (base + 2 < NN) v2 = counts[base + 2];
        if (base + 3 < NN) v3 = counts[base + 3];
    }
    const int s = v0 + v1 + v2 + v3;
    const int lane = t & 63, wid = t >> 6;
    int inc = s;
    #pragma unroll
    for (int off = 1; off < 64; off <<= 1) {
        int n = __shfl_up(inc, off, 64);
        if (lane >= off) inc += n;
    }
    __shared__ int wsum[4];
    if (lane == 63) wsum[wid] = inc;
    __syncthreads();
    int wbase = 0;
    for (int w = 0; w < wid; w++) wbase += wsum[w];
    const int texcl = wbase + inc - s;
    if (base     < NN) excl[base]     = texcl;
    if (base + 1 < NN) excl[base + 1] = texcl + v0;
    if (base + 2 < NN) excl[base + 2] = texcl + v0 + v1;
    if (base + 3 < NN) excl[base + 3] = texcl + v0 + v1 + v2;
    if (t == 255) blocksums[b] = wbase + inc;
}

__global__ __launch_bounds__(64) void scan2_kernel(const int* __restrict__ blocksums,
                                                   int* __restrict__ blockoff) {
    const int t = threadIdx.x;
    int v = (t < NSB) ? blocksums[t] : 0;
    int inc = v;
    #pragma unroll
    for (int off = 1; off < 64; off <<= 1) {
        int n = __shfl_up(inc, off, 64);
        if (t >= off) inc += n;
    }
    if (t < NSB) blockoff[t] = inc - v;
}

__global__ void scan3_kernel(const int* __restrict__ counts, const int* __restrict__ excl,
                             const int* __restrict__ blockoff, int* __restrict__ offsets,
                             int* __restrict__ cursor, float* __restrict__ dinv) {
    const int i = blockIdx.x * blockDim.x + threadIdx.x;
    if (i < NN) {
        const int o = excl[i] + blockoff[i >> 10];
        offsets[i] = o;
        cursor[i] = o;
        dinv[i] = rsqrtf((float)counts[i] + 1.0f);  // deg includes self-loop
    }
    if (i == 0) offsets[NN] = NE;
}

// Packed edge record: .x = __int_as_float(src), .y = dinv[src]*dinv[dst].
// One 8B scattered store per edge (halves dirty-line traffic vs two arrays).
__global__ void fill_kernel(const int* __restrict__ row, const int* __restrict__ col,
                            const float* __restrict__ dinv, int* __restrict__ cursor,
                            float2* __restrict__ csr) {
    int i = blockIdx.x * blockDim.x + threadIdx.x;
    if (i < NE) {
        int r = row[i], c = col[i];
        int p = atomicAdd(&cursor[c], 1);
        csr[p] = make_float2(__int_as_float(r), dinv[r] * dinv[c]);
    }
}

// ---------------- dense GEMM: H = A @ W  (fp32 VALU) ----------------
// W-only LDS (64KB) -> 2 blocks/CU. A read via L1 broadcast (lanes sharing
// a row-group hit the same address). 128 rows x 128 cols per block,
// 8x8 register tile per thread.

__global__ __launch_bounds__(256) void gemm_kernel(const float* __restrict__ A,
                                                   const float* __restrict__ W,
                                                   float* __restrict__ H) {
    __shared__ float Ws[128 * 128];  // [k][j]
    const int t = threadIdx.x;
    const int row0 = blockIdx.x * 128;

    const float4* W4 = (const float4*)W;
    float4* Ws4 = (float4*)Ws;
    #pragma unroll 4
    for (int i = t; i < 4096; i += 256) Ws4[i] = W4[i];
    __syncthreads();

    const int rg = t >> 4;   // 16 row-groups of 8 rows
    const int jc = t & 15;   // 16 col-groups of 8 cols
    const float4* A4 = (const float4*)A;
    int aoff[8];  // float4-unit offsets of this thread's 8 rows (clamped)
    #pragma unroll
    for (int m = 0; m < 8; m++) {
        int gr = row0 + 8 * rg + m;
        if (gr >= NN) gr = NN - 1;
        aoff[m] = gr * 32;
    }

    float acc[8][8];
    #pragma unroll
    for (int m = 0; m < 8; m++)
        #pragma unroll
        for (int c = 0; c < 8; c++) acc[m][c] = 0.0f;

    for (int k4 = 0; k4 < 32; k4++) {
        float4 a[8];
        #pragma unroll
        for (int m = 0; m < 8; m++) a[m] = A4[aoff[m] + k4];
        #pragma unroll
        for (int kk = 0; kk < 4; kk++) {
            int k = 4 * k4 + kk;
            float4 w0 = Ws4[k * 32 + jc * 2];
            float4 w1 = Ws4[k * 32 + jc * 2 + 1];
            #pragma unroll
            for (int m = 0; m < 8; m++) {
                float av = (kk == 0) ? a[m].x : (kk == 1) ? a[m].y
                         : (kk == 2) ? a[m].z : a[m].w;
                acc[m][0] += av * w0.x;
                acc[m][1] += av * w0.y;
                acc[m][2] += av * w0.z;
                acc[m][3] += av * w0.w;
                acc[m][4] += av * w1.x;
                acc[m][5] += av * w1.y;
                acc[m][6] += av * w1.z;
                acc[m][7] += av * w1.w;
            }
        }
    }

    #pragma unroll
    for (int m = 0; m < 8; m++) {
        int gr = row0 + 8 * rg + m;
        if (gr < NN) {
            float4* Hp = (float4*)(H + (size_t)gr * D + jc * 8);
            Hp[0] = make_float4(acc[m][0], acc[m][1], acc[m][2], acc[m][3]);
            Hp[1] = make_float4(acc[m][4], acc[m][5], acc[m][6], acc[m][7]);
        }
    }
}

// ---------------- aggregation ----------------
// One node per wave64 (no cross-node divergence), lane l owns feature pair 2l.
// 4-edge unroll with 4 accumulators -> 4 outstanding 512B gathers per wave.

__global__ __launch_bounds__(256) void agg_kernel(const float* __restrict__ h,
                                                  const int* __restrict__ offsets,
                                                  const float2* __restrict__ csr,
                                                  const float* __restrict__ dinv,
                                                  const float* __restrict__ bias,
                                                  float* __restrict__ out,
                                                  const int relu) {
    const int node = blockIdx.x * 4 + (threadIdx.x >> 6);
    const int l = threadIdx.x & 63;
    if (node >= NN) return;
    const float2* h2 = (const float2*)h;
    const float di = dinv[node];
    const float sw = di * di;
    float2 hv = h2[(size_t)node * 64 + l];
    float2 a0 = make_float2(sw * hv.x, sw * hv.y);
    float2 a1 = make_float2(0.f, 0.f);
    float2 a2 = make_float2(0.f, 0.f);
    float2 a3 = make_float2(0.f, 0.f);
    const int e0 = offsets[node];
    const int e1 = offsets[node + 1];
    int e = e0;
    for (; e + 4 <= e1; e += 4) {
        float2 r0 = csr[e + 0];
        float2 r1 = csr[e + 1];
        float2 r2 = csr[e + 2];
        float2 r3 = csr[e + 3];
        float2 v0 = h2[(size_t)__float_as_int(r0.x) * 64 + l];
        float2 v1 = h2[(size_t)__float_as_int(r1.x) * 64 + l];
        float2 v2 = h2[(size_t)__float_as_int(r2.x) * 64 + l];
        float2 v3 = h2[(size_t)__float_as_int(r3.x) * 64 + l];
        a0.x += r0.y * v0.x; a0.y += r0.y * v0.y;
        a1.x += r1.y * v1.x; a1.y += r1.y * v1.y;
        a2.x += r2.y * v2.x; a2.y += r2.y * v2.y;
        a3.x += r3.y * v3.x; a3.y += r3.y * v3.y;
    }
    for (; e < e1; e++) {
        float2 r = csr[e];
        float2 v = h2[(size_t)__float_as_int(r.x) * 64 + l];
        a0.x += r.y * v.x; a0.y += r.y * v.y;
    }
    const float2* b2p = (const float2*)bias;
    float2 bv = b2p[l];
    float2 res;
    res.x = (a0.x + a1.x) + (a2.x + a3.x) + bv.x;
    res.y = (a0.y + a1.y) + (a2.y + a3.y) + bv.y;
    if (relu) {
        res.x = fmaxf(res.x, 0.f);
        res.y = fmaxf(res.y, 0.f);
    }
    ((float2*)out)[(size_t)node * 64 + l] = res;
}

// ---------------- launch ----------------

extern "C" void kernel_launch(void* const* d_in, const int* in_sizes, int n_in,
                              void* d_out, int out_size, void* d_ws, size_t ws_size,
                              hipStream_t stream) {
    (void)in_sizes; (void)n_in; (void)out_size; (void)ws_size;
    const float* x  = (const float*)d_in[0];
    const int*   ei = (const int*)d_in[1];
    const float* W1 = (const float*)d_in[2];
    const float* b1 = (const float*)d_in[3];
    const float* W2 = (const float*)d_in[4];
    const float* b2 = (const float*)d_in[5];
    const float* W3 = (const float*)d_in[6];
    const float* b3 = (const float*)d_in[7];
    const int* row = ei;
    const int* col = ei + NE;
    float* outp = (float*)d_out;

    char* ws = (char*)d_ws;
    size_t off = 0;
    auto walloc = [&](size_t bytes) -> void* {
        void* p = ws + off;
        off = (off + bytes + 255) & ~(size_t)255;
        return p;
    };
    int*    counts   = (int*)walloc(NN * 4);
    int*    excl     = (int*)walloc(NN * 4);
    int*    blocksums= (int*)walloc(NSB * 4);
    int*    blockoff = (int*)walloc(NSB * 4);
    int*    offsets  = (int*)walloc((NN + 1) * 4);
    int*    cursor   = (int*)walloc(NN * 4);
    float*  dinv     = (float*)walloc(NN * 4);
    float2* csr      = (float2*)walloc((size_t)NE * 8);
    float*  hbuf     = (float*)walloc((size_t)NN * D * 4);
    float*  act      = (float*)walloc((size_t)NN * D * 4);

    hipMemsetAsync(counts, 0, NN * 4, stream);
    count_kernel<<<(NE + 255) / 256, 256, 0, stream>>>(col, counts);
    scan1_kernel<<<NSB, 256, 0, stream>>>(counts, excl, blocksums);
    scan2_kernel<<<1, 64, 0, stream>>>(blocksums, blockoff);
    scan3_kernel<<<(NN + 255) / 256, 256, 0, stream>>>(counts, excl, blockoff,
                                                       offsets, cursor, dinv);
    fill_kernel<<<(NE + 255) / 256, 256, 0, stream>>>(row, col, dinv, cursor, csr);

    const int gblocks = (NN + 127) / 128;
    // layer 1
    gemm_kernel<<<gblocks, 256, 0, stream>>>(x, W1, hbuf);
    agg_kernel<<<(NN + 3) / 4, 256, 0, stream>>>(hbuf, offsets, csr, dinv, b1, act, 1);
    // layer 2
    gemm_kernel<<<gblocks, 256, 0, stream>>>(act, W2, hbuf);
    agg_kernel<<<(NN + 3) / 4, 256, 0, stream>>>(hbuf, offsets, csr, dinv, b2, act, 1);
    // layer 3 (no relu)
    gemm_kernel<<<gblocks, 256, 0, stream>>>(act, W3, hbuf);
    agg_kernel<<<(NN + 3) / 4, 256, 0, stream>>>(hbuf, offsets, csr, dinv, b3, outp, 0);
}

// Round 5
// 315.252 us; speedup vs baseline: 1.3572x; 1.0065x over previous
//
#include <hip/hip_runtime.h>
#include <hip/hip_bf16.h>
#include <hip/hip_fp16.h>

#define NN 50000
#define NE 625000
#define D 128
#define SCAN_BLK 1024  // elements per scan1 block
#define NSB ((NN + SCAN_BLK - 1) / SCAN_BLK)  // 49

// ---------------- CSR build ----------------

__global__ void count_kernel(const int* __restrict__ col, int* __restrict__ counts) {
    int i = blockIdx.x * blockDim.x + threadIdx.x;
    if (i < NE) atomicAdd(&counts[col[i]], 1);
}

__global__ __launch_bounds__(256) void scan1_kernel(const int* __restrict__ counts,
                                                    int* __restrict__ excl,
                                                    int* __restrict__ blocksums) {
    const int b = blockIdx.x, t = threadIdx.x;
    const int base = b * SCAN_BLK + t * 4;
    int v0 = 0, v1 = 0, v2 = 0, v3 = 0;
    if (base + 3 < NN) {
        int4 c = *(const int4*)(counts + base);
        v0 = c.x; v1 = c.y; v2 = c.z; v3 = c.w;
    } else {
        if (base     < NN) v0 = counts[base];
        if (base + 1 < NN) v1 = counts[base + 1];
        if (base + 2 < NN) v2 = counts[base + 2];
        if (base + 3 < NN) v3 = counts[base + 3];
    }
    const int s = v0 + v1 + v2 + v3;
    const int lane = t & 63, wid = t >> 6;
    int inc = s;
    #pragma unroll
    for (int off = 1; off < 64; off <<= 1) {
        int n = __shfl_up(inc, off, 64);
        if (lane >= off) inc += n;
    }
    __shared__ int wsum[4];
    if (lane == 63) wsum[wid] = inc;
    __syncthreads();
    int wbase = 0;
    for (int w = 0; w < wid; w++) wbase += wsum[w];
    const int texcl = wbase + inc - s;
    if (base     < NN) excl[base]     = texcl;
    if (base + 1 < NN) excl[base + 1] = texcl + v0;
    if (base + 2 < NN) excl[base + 2] = texcl + v0 + v1;
    if (base + 3 < NN) excl[base + 3] = texcl + v0 + v1 + v2;
    if (t == 255) blocksums[b] = wbase + inc;
}

__global__ __launch_bounds__(64) void scan2_kernel(const int* __restrict__ blocksums,
                                                   int* __restrict__ blockoff) {
    const int t = threadIdx.x;
    int v = (t < NSB) ? blocksums[t] : 0;
    int inc = v;
    #pragma unroll
    for (int off = 1; off < 64; off <<= 1) {
        int n = __shfl_up(inc, off, 64);
        if (t >= off) inc += n;
    }
    if (t < NSB) blockoff[t] = inc - v;
}

__global__ void scan3_kernel(const int* __restrict__ counts, const int* __restrict__ excl,
                             const int* __restrict__ blockoff, int* __restrict__ offsets,
                             int* __restrict__ cursor, float* __restrict__ dinv) {
    const int i = blockIdx.x * blockDim.x + threadIdx.x;
    if (i < NN) {
        const int o = excl[i] + blockoff[i >> 10];
        offsets[i] = o;
        cursor[i] = o;
        dinv[i] = rsqrtf((float)counts[i] + 1.0f);  // deg includes self-loop
    }
    if (i == 0) offsets[NN] = NE;
}

// Packed edge record: .x = __int_as_float(src), .y = dinv[src]*dinv[dst].
__global__ void fill_kernel(const int* __restrict__ row, const int* __restrict__ col,
                            const float* __restrict__ dinv, int* __restrict__ cursor,
                            float2* __restrict__ csr) {
    int i = blockIdx.x * blockDim.x + threadIdx.x;
    if (i < NE) {
        int r = row[i], c = col[i];
        int p = atomicAdd(&cursor[c], 1);
        csr[p] = make_float2(__int_as_float(r), dinv[r] * dinv[c]);
    }
}

// ---------------- dense GEMM: H = A @ W  (fp32 VALU) ----------------
// W-only LDS (64KB) -> 2 blocks/CU. Also emits fp16 copy of H for the
// aggregation gather (halves gather line traffic; fp16 keeps 10 mantissa bits).

__global__ __launch_bounds__(256) void gemm_kernel(const float* __restrict__ A,
                                                   const float* __restrict__ W,
                                                   float* __restrict__ H,
                                                   uint32_t* __restrict__ Hh) {
    __shared__ float Ws[128 * 128];  // [k][j]
    const int t = threadIdx.x;
    const int row0 = blockIdx.x * 128;

    const float4* W4 = (const float4*)W;
    float4* Ws4 = (float4*)Ws;
    #pragma unroll 4
    for (int i = t; i < 4096; i += 256) Ws4[i] = W4[i];
    __syncthreads();

    const int rg = t >> 4;   // 16 row-groups of 8 rows
    const int jc = t & 15;   // 16 col-groups of 8 cols
    const float4* A4 = (const float4*)A;
    int aoff[8];
    #pragma unroll
    for (int m = 0; m < 8; m++) {
        int gr = row0 + 8 * rg + m;
        if (gr >= NN) gr = NN - 1;
        aoff[m] = gr * 32;
    }

    float acc[8][8];
    #pragma unroll
    for (int m = 0; m < 8; m++)
        #pragma unroll
        for (int c = 0; c < 8; c++) acc[m][c] = 0.0f;

    for (int k4 = 0; k4 < 32; k4++) {
        float4 a[8];
        #pragma unroll
        for (int m = 0; m < 8; m++) a[m] = A4[aoff[m] + k4];
        #pragma unroll
        for (int kk = 0; kk < 4; kk++) {
            int k = 4 * k4 + kk;
            float4 w0 = Ws4[k * 32 + jc * 2];
            float4 w1 = Ws4[k * 32 + jc * 2 + 1];
            #pragma unroll
            for (int m = 0; m < 8; m++) {
                float av = (kk == 0) ? a[m].x : (kk == 1) ? a[m].y
                         : (kk == 2) ? a[m].z : a[m].w;
                acc[m][0] += av * w0.x;
                acc[m][1] += av * w0.y;
                acc[m][2] += av * w0.z;
                acc[m][3] += av * w0.w;
                acc[m][4] += av * w1.x;
                acc[m][5] += av * w1.y;
                acc[m][6] += av * w1.z;
                acc[m][7] += av * w1.w;
            }
        }
    }

    #pragma unroll
    for (int m = 0; m < 8; m++) {
        int gr = row0 + 8 * rg + m;
        if (gr < NN) {
            float4* Hp = (float4*)(H + (size_t)gr * D + jc * 8);
            Hp[0] = make_float4(acc[m][0], acc[m][1], acc[m][2], acc[m][3]);
            Hp[1] = make_float4(acc[m][4], acc[m][5], acc[m][6], acc[m][7]);
            __half2 h0 = __float22half2_rn(make_float2(acc[m][0], acc[m][1]));
            __half2 h1 = __float22half2_rn(make_float2(acc[m][2], acc[m][3]));
            __half2 h2 = __float22half2_rn(make_float2(acc[m][4], acc[m][5]));
            __half2 h3 = __float22half2_rn(make_float2(acc[m][6], acc[m][7]));
            uint4 p;
            p.x = *(const uint32_t*)&h0;
            p.y = *(const uint32_t*)&h1;
            p.z = *(const uint32_t*)&h2;
            p.w = *(const uint32_t*)&h3;
            // row stride = 64 uint32 (128 fp16 features)
            *(uint4*)(Hh + (size_t)gr * 64 + jc * 4) = p;
        }
    }
}

// ---------------- aggregation ----------------
// One node per wave64; lane l owns features 2l,2l+1. Neighbor rows gathered
// from fp16 copy (256B/row). 8-deep masked unroll: all loads of a batch are
// independent (OOB slots clamp index, weight=0). Self term from fp32 h.

__global__ __launch_bounds__(256) void agg_kernel(const float* __restrict__ h,
                                                  const uint32_t* __restrict__ hh,
                                                  const int* __restrict__ offsets,
                                                  const float2* __restrict__ csr,
                                                  const float* __restrict__ dinv,
                                                  const float* __restrict__ bias,
                                                  float* __restrict__ out,
                                                  const int relu) {
    const int node = blockIdx.x * 4 + (threadIdx.x >> 6);
    const int l = threadIdx.x & 63;
    if (node >= NN) return;
    const float di = dinv[node];
    const float sw = di * di;

    const uint64_t* hu = (const uint64_t*)h;  // row stride 64 u64
    uint64_t selfu = __builtin_nontemporal_load(hu + (size_t)node * 64 + l);
    float2 hv;
    hv.x = __uint_as_float((uint32_t)selfu);
    hv.y = __uint_as_float((uint32_t)(selfu >> 32));

    float2 acc[8];
    #pragma unroll
    for (int k = 0; k < 8; k++) acc[k] = make_float2(0.f, 0.f);
    acc[0].x = sw * hv.x;
    acc[0].y = sw * hv.y;

    const int e0 = offsets[node];
    const int e1 = offsets[node + 1];
    const uint64_t* csru = (const uint64_t*)csr;

    for (int e = e0; e < e1; e += 8) {
        #pragma unroll
        for (int k = 0; k < 8; k++) {
            const int ee = e + k;
            const bool valid = ee < e1;
            const int ec = valid ? ee : (e1 - 1);
            uint64_t r = __builtin_nontemporal_load(csru + ec);
            int s = (int)(uint32_t)r;
            float w = valid ? __uint_as_float((uint32_t)(r >> 32)) : 0.0f;
            uint32_t v = hh[(size_t)s * 64 + l];
            __half2 vh = *(const __half2*)&v;
            float2 vf = __half22float2(vh);
            acc[k].x += w * vf.x;
            acc[k].y += w * vf.y;
        }
    }

    const float2* b2p = (const float2*)bias;
    float2 bv = b2p[l];
    float rx = ((acc[0].x + acc[1].x) + (acc[2].x + acc[3].x)) +
               ((acc[4].x + acc[5].x) + (acc[6].x + acc[7].x)) + bv.x;
    float ry = ((acc[0].y + acc[1].y) + (acc[2].y + acc[3].y)) +
               ((acc[4].y + acc[5].y) + (acc[6].y + acc[7].y)) + bv.y;
    if (relu) {
        rx = fmaxf(rx, 0.f);
        ry = fmaxf(ry, 0.f);
    }
    uint64_t o = (uint64_t)__float_as_uint(rx) | ((uint64_t)__float_as_uint(ry) << 32);
    __builtin_nontemporal_store(o, (uint64_t*)out + (size_t)node * 64 + l);
}

// ---------------- launch ----------------

extern "C" void kernel_launch(void* const* d_in, const int* in_sizes, int n_in,
                              void* d_out, int out_size, void* d_ws, size_t ws_size,
                              hipStream_t stream) {
    (void)in_sizes; (void)n_in; (void)out_size; (void)ws_size;
    const float* x  = (const float*)d_in[0];
    const int*   ei = (const int*)d_in[1];
    const float* W1 = (const float*)d_in[2];
    const float* b1 = (const float*)d_in[3];
    const float* W2 = (const float*)d_in[4];
    const float* b2 = (const float*)d_in[5];
    const float* W3 = (const float*)d_in[6];
    const float* b3 = (const float*)d_in[7];
    const int* row = ei;
    const int* col = ei + NE;
    float* outp = (float*)d_out;

    char* ws = (char*)d_ws;
    size_t off = 0;
    auto walloc = [&](size_t bytes) -> void* {
        void* p = ws + off;
        off = (off + bytes + 255) & ~(size_t)255;
        return p;
    };
    int*      counts   = (int*)walloc(NN * 4);
    int*      excl     = (int*)walloc(NN * 4);
    int*      blocksums= (int*)walloc(NSB * 4);
    int*      blockoff = (int*)walloc(NSB * 4);
    int*      offsets  = (int*)walloc((NN + 1) * 4);
    int*      cursor   = (int*)walloc(NN * 4);
    float*    dinv     = (float*)walloc(NN * 4);
    float2*   csr      = (float2*)walloc((size_t)NE * 8);
    float*    hbuf     = (float*)walloc((size_t)NN * D * 4);
    float*    act      = (float*)walloc((size_t)NN * D * 4);
    uint32_t* hh16     = (uint32_t*)walloc((size_t)NN * D * 2);

    hipMemsetAsync(counts, 0, NN * 4, stream);
    count_kernel<<<(NE + 255) / 256, 256, 0, stream>>>(col, counts);
    scan1_kernel<<<NSB, 256, 0, stream>>>(counts, excl, blocksums);
    scan2_kernel<<<1, 64, 0, stream>>>(blocksums, blockoff);
    scan3_kernel<<<(NN + 255) / 256, 256, 0, stream>>>(counts, excl, blockoff,
                                                       offsets, cursor, dinv);
    fill_kernel<<<(NE + 255) / 256, 256, 0, stream>>>(row, col, dinv, cursor, csr);

    const int gblocks = (NN + 127) / 128;
    const int ablocks = (NN + 3) / 4;
    // layer 1
    gemm_kernel<<<gblocks, 256, 0, stream>>>(x, W1, hbuf, hh16);
    agg_kernel<<<ablocks, 256, 0, stream>>>(hbuf, hh16, offsets, csr, dinv, b1, act, 1);
    // layer 2
    gemm_kernel<<<gblocks, 256, 0, stream>>>(act, W2, hbuf, hh16);
    agg_kernel<<<ablocks, 256, 0, stream>>>(hbuf, hh16, offsets, csr, dinv, b2, act, 1);
    // layer 3 (no relu)
    gemm_kernel<<<gblocks, 256, 0, stream>>>(act, W3, hbuf, hh16);
    agg_kernel<<<ablocks, 256, 0, stream>>>(hbuf, hh16, offsets, csr, dinv, b3, outp, 0);
}

// Round 6
// 258.104 us; speedup vs baseline: 1.6577x; 1.2214x over previous
//
#include <hip/hip_runtime.h>
#include <hip/hip_fp16.h>

#define NN 50000
#define NE 625000
#define D 128
#define SCAN_BLK 1024  // elements per scan1 block
#define NSB ((NN + SCAN_BLK - 1) / SCAN_BLK)  // 49

// ---------------- CSR build ----------------

__global__ void count_kernel(const int* __restrict__ col, int* __restrict__ counts) {
    int i = blockIdx.x * blockDim.x + threadIdx.x;
    if (i < NE) atomicAdd(&counts[col[i]], 1);
}

__global__ __launch_bounds__(256) void scan1_kernel(const int* __restrict__ counts,
                                                    int* __restrict__ excl,
                                                    int* __restrict__ blocksums) {
    const int b = blockIdx.x, t = threadIdx.x;
    const int base = b * SCAN_BLK + t * 4;
    int v0 = 0, v1 = 0, v2 = 0, v3 = 0;
    if (base + 3 < NN) {
        int4 c = *(const int4*)(counts + base);
        v0 = c.x; v1 = c.y; v2 = c.z; v3 = c.w;
    } else {
        if (base     < NN) v0 = counts[base];
        if (base + 1 < NN) v1 = counts[base + 1];
        if (base + 2 < NN) v2 = counts[base + 2];
        if (base + 3 < NN) v3 = counts[base + 3];
    }
    const int s = v0 + v1 + v2 + v3;
    const int lane = t & 63, wid = t >> 6;
    int inc = s;
    #pragma unroll
    for (int off = 1; off < 64; off <<= 1) {
        int n = __shfl_up(inc, off, 64);
        if (lane >= off) inc += n;
    }
    __shared__ int wsum[4];
    if (lane == 63) wsum[wid] = inc;
    __syncthreads();
    int wbase = 0;
    for (int w = 0; w < wid; w++) wbase += wsum[w];
    const int texcl = wbase + inc - s;
    if (base     < NN) excl[base]     = texcl;
    if (base + 1 < NN) excl[base + 1] = texcl + v0;
    if (base + 2 < NN) excl[base + 2] = texcl + v0 + v1;
    if (base + 3 < NN) excl[base + 3] = texcl + v0 + v1 + v2;
    if (t == 255) blocksums[b] = wbase + inc;
}

__global__ __launch_bounds__(64) void scan2_kernel(const int* __restrict__ blocksums,
                                                   int* __restrict__ blockoff) {
    const int t = threadIdx.x;
    int v = (t < NSB) ? blocksums[t] : 0;
    int inc = v;
    #pragma unroll
    for (int off = 1; off < 64; off <<= 1) {
        int n = __shfl_up(inc, off, 64);
        if (t >= off) inc += n;
    }
    if (t < NSB) blockoff[t] = inc - v;
}

__global__ void scan3_kernel(const int* __restrict__ counts, const int* __restrict__ excl,
                             const int* __restrict__ blockoff, int* __restrict__ offsets,
                             int* __restrict__ cursor, float* __restrict__ dinv) {
    const int i = blockIdx.x * blockDim.x + threadIdx.x;
    if (i < NN) {
        const int o = excl[i] + blockoff[i >> 10];
        offsets[i] = o;
        cursor[i] = o;
        dinv[i] = rsqrtf((float)counts[i] + 1.0f);  // deg includes self-loop
    }
    if (i == 0) offsets[NN] = NE;
}

// Packed edge record: lo32 = src index, hi32 = dinv[src]*dinv[dst] bits.
__global__ void fill_kernel(const int* __restrict__ row, const int* __restrict__ col,
                            const float* __restrict__ dinv, int* __restrict__ cursor,
                            float2* __restrict__ csr) {
    int i = blockIdx.x * blockDim.x + threadIdx.x;
    if (i < NE) {
        int r = row[i], c = col[i];
        int p = atomicAdd(&cursor[c], 1);
        csr[p] = make_float2(__int_as_float(r), dinv[r] * dinv[c]);
    }
}

// ---------------- dense GEMM: Hh(fp16) = A(fp32) @ W ----------------
// W-only LDS (64KB) -> 2 blocks/CU. Output ONLY the fp16 copy (the fp32
// result is never consumed anywhere anymore).

__global__ __launch_bounds__(256) void gemm_kernel(const float* __restrict__ A,
                                                   const float* __restrict__ W,
                                                   uint32_t* __restrict__ Hh) {
    __shared__ float Ws[128 * 128];  // [k][j]
    const int t = threadIdx.x;
    const int row0 = blockIdx.x * 128;

    const float4* W4 = (const float4*)W;
    float4* Ws4 = (float4*)Ws;
    #pragma unroll 4
    for (int i = t; i < 4096; i += 256) Ws4[i] = W4[i];
    __syncthreads();

    const int rg = t >> 4;   // 16 row-groups of 8 rows
    const int jc = t & 15;   // 16 col-groups of 8 cols
    const float4* A4 = (const float4*)A;
    int aoff[8];
    #pragma unroll
    for (int m = 0; m < 8; m++) {
        int gr = row0 + 8 * rg + m;
        if (gr >= NN) gr = NN - 1;
        aoff[m] = gr * 32;
    }

    float acc[8][8];
    #pragma unroll
    for (int m = 0; m < 8; m++)
        #pragma unroll
        for (int c = 0; c < 8; c++) acc[m][c] = 0.0f;

    for (int k4 = 0; k4 < 32; k4++) {
        float4 a[8];
        #pragma unroll
        for (int m = 0; m < 8; m++) a[m] = A4[aoff[m] + k4];
        #pragma unroll
        for (int kk = 0; kk < 4; kk++) {
            int k = 4 * k4 + kk;
            float4 w0 = Ws4[k * 32 + jc * 2];
            float4 w1 = Ws4[k * 32 + jc * 2 + 1];
            #pragma unroll
            for (int m = 0; m < 8; m++) {
                float av = (kk == 0) ? a[m].x : (kk == 1) ? a[m].y
                         : (kk == 2) ? a[m].z : a[m].w;
                acc[m][0] += av * w0.x;
                acc[m][1] += av * w0.y;
                acc[m][2] += av * w0.z;
                acc[m][3] += av * w0.w;
                acc[m][4] += av * w1.x;
                acc[m][5] += av * w1.y;
                acc[m][6] += av * w1.z;
                acc[m][7] += av * w1.w;
            }
        }
    }

    #pragma unroll
    for (int m = 0; m < 8; m++) {
        int gr = row0 + 8 * rg + m;
        if (gr < NN) {
            __half2 h0 = __float22half2_rn(make_float2(acc[m][0], acc[m][1]));
            __half2 h1 = __float22half2_rn(make_float2(acc[m][2], acc[m][3]));
            __half2 h2 = __float22half2_rn(make_float2(acc[m][4], acc[m][5]));
            __half2 h3 = __float22half2_rn(make_float2(acc[m][6], acc[m][7]));
            uint4 p;
            p.x = *(const uint32_t*)&h0;
            p.y = *(const uint32_t*)&h1;
            p.z = *(const uint32_t*)&h2;
            p.w = *(const uint32_t*)&h3;
            // row stride = 64 uint32 (128 fp16 features)
            *(uint4*)(Hh + (size_t)gr * 64 + jc * 4) = p;
        }
    }
}

// ---------------- aggregation ----------------
// One node per wave64, PAIR-SPLIT: lanes 0-31 handle even edge of a pair,
// lanes 32-63 the odd edge. Each lane loads uint2 = 4 fp16 features, so one
// gather instruction serves TWO edges. csr records for batch k+1 are
// prefetched while batch k's gathers are in flight (breaks the rec->gather
// dependent chain). Self term also from fp16 copy. fp32 accumulate.

static __device__ __forceinline__ void proc_edge(uint64_t r, bool valid, int lh,
                                                 const uint2* __restrict__ hh2,
                                                 float4& acc) {
    const int s = (int)(uint32_t)r;
    const float w = valid ? __uint_as_float((uint32_t)(r >> 32)) : 0.0f;
    uint2 v = hh2[(size_t)s * 32 + lh];
    float2 lo = __half22float2(*(const __half2*)&v.x);
    float2 hi = __half22float2(*(const __half2*)&v.y);
    acc.x += w * lo.x;
    acc.y += w * lo.y;
    acc.z += w * hi.x;
    acc.w += w * hi.y;
}

__global__ __launch_bounds__(256) void agg_kernel(const uint2* __restrict__ hh2,
                                                  const int* __restrict__ offsets,
                                                  const uint64_t* __restrict__ csru,
                                                  const float* __restrict__ dinv,
                                                  const float* __restrict__ bias,
                                                  float* __restrict__ out,
                                                  const int relu) {
    const int node = blockIdx.x * 4 + (threadIdx.x >> 6);
    if (node >= NN) return;
    const int l = threadIdx.x & 63;
    const int half = l >> 5, lh = l & 31;
    const float di = dinv[node];
    const float sw = di * di;
    const int e0 = offsets[node];
    const int e1 = offsets[node + 1];

    float4 acc0 = make_float4(0.f, 0.f, 0.f, 0.f);
    float4 acc1 = make_float4(0.f, 0.f, 0.f, 0.f);
    float4 acc2 = make_float4(0.f, 0.f, 0.f, 0.f);
    float4 acc3 = make_float4(0.f, 0.f, 0.f, 0.f);

    if (e0 < e1) {
        const int elast = e1 - 1;
        // prologue: records for first batch (8 edges = 4 pair-slots)
        uint64_t r0 = csru[min(e0 + 0 + half, elast)];
        uint64_t r1 = csru[min(e0 + 2 + half, elast)];
        uint64_t r2 = csru[min(e0 + 4 + half, elast)];
        uint64_t r3 = csru[min(e0 + 6 + half, elast)];
        for (int eb = e0; eb < e1; eb += 8) {
            const int nb = eb + 8;
            // prefetch next batch's records (clamped; harmless past end)
            uint64_t n0 = csru[min(nb + 0 + half, elast)];
            uint64_t n1 = csru[min(nb + 2 + half, elast)];
            uint64_t n2 = csru[min(nb + 4 + half, elast)];
            uint64_t n3 = csru[min(nb + 6 + half, elast)];
            proc_edge(r0, eb + 0 + half < e1, lh, hh2, acc0);
            proc_edge(r1, eb + 2 + half < e1, lh, hh2, acc1);
            proc_edge(r2, eb + 4 + half < e1, lh, hh2, acc2);
            proc_edge(r3, eb + 6 + half < e1, lh, hh2, acc3);
            r0 = n0; r1 = n1; r2 = n2; r3 = n3;
        }
    }

    float4 s;
    s.x = (acc0.x + acc1.x) + (acc2.x + acc3.x);
    s.y = (acc0.y + acc1.y) + (acc2.y + acc3.y);
    s.z = (acc0.z + acc1.z) + (acc2.z + acc3.z);
    s.w = (acc0.w + acc1.w) + (acc2.w + acc3.w);
    s.x += __shfl_xor(s.x, 32, 64);
    s.y += __shfl_xor(s.y, 32, 64);
    s.z += __shfl_xor(s.z, 32, 64);
    s.w += __shfl_xor(s.w, 32, 64);

    // self term (fp16 copy) + bias
    uint2 sv = hh2[(size_t)node * 32 + lh];
    float2 slo = __half22float2(*(const __half2*)&sv.x);
    float2 shi = __half22float2(*(const __half2*)&sv.y);
    float4 bv = ((const float4*)bias)[lh];
    s.x += sw * slo.x + bv.x;
    s.y += sw * slo.y + bv.y;
    s.z += sw * shi.x + bv.z;
    s.w += sw * shi.y + bv.w;
    if (relu) {
        s.x = fmaxf(s.x, 0.f);
        s.y = fmaxf(s.y, 0.f);
        s.z = fmaxf(s.z, 0.f);
        s.w = fmaxf(s.w, 0.f);
    }
    if (half == 0) ((float4*)out)[(size_t)node * 32 + lh] = s;
}

// ---------------- launch ----------------

extern "C" void kernel_launch(void* const* d_in, const int* in_sizes, int n_in,
                              void* d_out, int out_size, void* d_ws, size_t ws_size,
                              hipStream_t stream) {
    (void)in_sizes; (void)n_in; (void)out_size; (void)ws_size;
    const float* x  = (const float*)d_in[0];
    const int*   ei = (const int*)d_in[1];
    const float* W1 = (const float*)d_in[2];
    const float* b1 = (const float*)d_in[3];
    const float* W2 = (const float*)d_in[4];
    const float* b2 = (const float*)d_in[5];
    const float* W3 = (const float*)d_in[6];
    const float* b3 = (const float*)d_in[7];
    const int* row = ei;
    const int* col = ei + NE;
    float* outp = (float*)d_out;

    char* ws = (char*)d_ws;
    size_t off = 0;
    auto walloc = [&](size_t bytes) -> void* {
        void* p = ws + off;
        off = (off + bytes + 255) & ~(size_t)255;
        return p;
    };
    int*      counts   = (int*)walloc(NN * 4);
    int*      excl     = (int*)walloc(NN * 4);
    int*      blocksums= (int*)walloc(NSB * 4);
    int*      blockoff = (int*)walloc(NSB * 4);
    int*      offsets  = (int*)walloc((NN + 1) * 4);
    int*      cursor   = (int*)walloc(NN * 4);
    float*    dinv     = (float*)walloc(NN * 4);
    float2*   csr      = (float2*)walloc((size_t)NE * 8);
    float*    act      = (float*)walloc((size_t)NN * D * 4);
    uint32_t* hh16     = (uint32_t*)walloc((size_t)NN * D * 2);

    hipMemsetAsync(counts, 0, NN * 4, stream);
    count_kernel<<<(NE + 255) / 256, 256, 0, stream>>>(col, counts);
    scan1_kernel<<<NSB, 256, 0, stream>>>(counts, excl, blocksums);
    scan2_kernel<<<1, 64, 0, stream>>>(blocksums, blockoff);
    scan3_kernel<<<(NN + 255) / 256, 256, 0, stream>>>(counts, excl, blockoff,
                                                       offsets, cursor, dinv);
    fill_kernel<<<(NE + 255) / 256, 256, 0, stream>>>(row, col, dinv, cursor, csr);

    const int gblocks = (NN + 127) / 128;
    const int ablocks = (NN + 3) / 4;
    const uint2* hh2 = (const uint2*)hh16;
    const uint64_t* csru = (const uint64_t*)csr;
    // layer 1
    gemm_kernel<<<gblocks, 256, 0, stream>>>(x, W1, hh16);
    agg_kernel<<<ablocks, 256, 0, stream>>>(hh2, offsets, csru, dinv, b1, act, 1);
    // layer 2
    gemm_kernel<<<gblocks, 256, 0, stream>>>(act, W2, hh16);
    agg_kernel<<<ablocks, 256, 0, stream>>>(hh2, offsets, csru, dinv, b2, act, 1);
    // layer 3 (no relu)
    gemm_kernel<<<gblocks, 256, 0, stream>>>(act, W3, hh16);
    agg_kernel<<<ablocks, 256, 0, stream>>>(hh2, offsets, csru, dinv, b3, outp, 0);
}

// Round 7
// 245.883 us; speedup vs baseline: 1.7401x; 1.0497x over previous
//
#include <hip/hip_runtime.h>
#include <hip/hip_fp16.h>

#define NN 50000
#define NE 625000
#define D 128
#define SCAN_BLK 1024  // elements per scan1 block
#define NSB ((NN + SCAN_BLK - 1) / SCAN_BLK)  // 49

// ---------------- CSR build ----------------

__global__ void zero_kernel(int4* __restrict__ p) {
    int i = blockIdx.x * blockDim.x + threadIdx.x;
    if (i < NN / 4 + 1) p[i] = make_int4(0, 0, 0, 0);  // NN/4=12500 exact; +1 pad slack
}

__global__ void count_kernel(const int* __restrict__ col, int* __restrict__ counts) {
    int i = blockIdx.x * blockDim.x + threadIdx.x;
    if (i < NE) atomicAdd(&counts[col[i]], 1);
}

__global__ __launch_bounds__(256) void scan1_kernel(const int* __restrict__ counts,
                                                    int* __restrict__ excl,
                                                    int* __restrict__ blocksums) {
    const int b = blockIdx.x, t = threadIdx.x;
    const int base = b * SCAN_BLK + t * 4;
    int v0 = 0, v1 = 0, v2 = 0, v3 = 0;
    if (base + 3 < NN) {
        int4 c = *(const int4*)(counts + base);
        v0 = c.x; v1 = c.y; v2 = c.z; v3 = c.w;
    } else {
        if (base     < NN) v0 = counts[base];
        if (base + 1 < NN) v1 = counts[base + 1];
        if (base + 2 < NN) v2 = counts[base + 2];
        if (base + 3 < NN) v3 = counts[base + 3];
    }
    const int s = v0 + v1 + v2 + v3;
    const int lane = t & 63, wid = t >> 6;
    int inc = s;
    #pragma unroll
    for (int off = 1; off < 64; off <<= 1) {
        int n = __shfl_up(inc, off, 64);
        if (lane >= off) inc += n;
    }
    __shared__ int wsum[4];
    if (lane == 63) wsum[wid] = inc;
    __syncthreads();
    int wbase = 0;
    for (int w = 0; w < wid; w++) wbase += wsum[w];
    const int texcl = wbase + inc - s;
    if (base     < NN) excl[base]     = texcl;
    if (base + 1 < NN) excl[base + 1] = texcl + v0;
    if (base + 2 < NN) excl[base + 2] = texcl + v0 + v1;
    if (base + 3 < NN) excl[base + 3] = texcl + v0 + v1 + v2;
    if (t == 255) blocksums[b] = wbase + inc;
}

__global__ __launch_bounds__(64) void scan2_kernel(const int* __restrict__ blocksums,
                                                   int* __restrict__ blockoff) {
    const int t = threadIdx.x;
    int v = (t < NSB) ? blocksums[t] : 0;
    int inc = v;
    #pragma unroll
    for (int off = 1; off < 64; off <<= 1) {
        int n = __shfl_up(inc, off, 64);
        if (t >= off) inc += n;
    }
    if (t < NSB) blockoff[t] = inc - v;
}

__global__ void scan3_kernel(const int* __restrict__ counts, const int* __restrict__ excl,
                             const int* __restrict__ blockoff, int* __restrict__ offsets,
                             int* __restrict__ cursor, float* __restrict__ dinv) {
    const int i = blockIdx.x * blockDim.x + threadIdx.x;
    if (i < NN) {
        const int o = excl[i] + blockoff[i >> 10];
        offsets[i] = o;
        cursor[i] = o;
        dinv[i] = rsqrtf((float)counts[i] + 1.0f);  // deg includes self-loop
    }
    if (i == 0) offsets[NN] = NE;
}

// Packed 4B edge record: lo16 = src index (NN<65536), hi16 = fp16 weight.
__global__ void fill_kernel(const int* __restrict__ row, const int* __restrict__ col,
                            const float* __restrict__ dinv, int* __restrict__ cursor,
                            uint32_t* __restrict__ csr) {
    int i = blockIdx.x * blockDim.x + threadIdx.x;
    if (i < NE) {
        int r = row[i], c = col[i];
        int p = atomicAdd(&cursor[c], 1);
        __half hw = __float2half_rn(dinv[r] * dinv[c]);
        csr[p] = (uint32_t)r | ((uint32_t)*(const unsigned short*)&hw << 16);
    }
}

// ---------------- dense GEMM: Hh(fp16) = A(fp32) @ W ----------------
// W-only LDS (64KB) -> 2 blocks/CU. Output only the fp16 copy.

__global__ __launch_bounds__(256) void gemm_kernel(const float* __restrict__ A,
                                                   const float* __restrict__ W,
                                                   uint32_t* __restrict__ Hh) {
    __shared__ float Ws[128 * 128];  // [k][j]
    const int t = threadIdx.x;
    const int row0 = blockIdx.x * 128;

    const float4* W4 = (const float4*)W;
    float4* Ws4 = (float4*)Ws;
    #pragma unroll 4
    for (int i = t; i < 4096; i += 256) Ws4[i] = W4[i];
    __syncthreads();

    const int rg = t >> 4;   // 16 row-groups of 8 rows
    const int jc = t & 15;   // 16 col-groups of 8 cols
    const float4* A4 = (const float4*)A;
    int aoff[8];
    #pragma unroll
    for (int m = 0; m < 8; m++) {
        int gr = row0 + 8 * rg + m;
        if (gr >= NN) gr = NN - 1;
        aoff[m] = gr * 32;
    }

    float acc[8][8];
    #pragma unroll
    for (int m = 0; m < 8; m++)
        #pragma unroll
        for (int c = 0; c < 8; c++) acc[m][c] = 0.0f;

    for (int k4 = 0; k4 < 32; k4++) {
        float4 a[8];
        #pragma unroll
        for (int m = 0; m < 8; m++) a[m] = A4[aoff[m] + k4];
        #pragma unroll
        for (int kk = 0; kk < 4; kk++) {
            int k = 4 * k4 + kk;
            float4 w0 = Ws4[k * 32 + jc * 2];
            float4 w1 = Ws4[k * 32 + jc * 2 + 1];
            #pragma unroll
            for (int m = 0; m < 8; m++) {
                float av = (kk == 0) ? a[m].x : (kk == 1) ? a[m].y
                         : (kk == 2) ? a[m].z : a[m].w;
                acc[m][0] += av * w0.x;
                acc[m][1] += av * w0.y;
                acc[m][2] += av * w0.z;
                acc[m][3] += av * w0.w;
                acc[m][4] += av * w1.x;
                acc[m][5] += av * w1.y;
                acc[m][6] += av * w1.z;
                acc[m][7] += av * w1.w;
            }
        }
    }

    #pragma unroll
    for (int m = 0; m < 8; m++) {
        int gr = row0 + 8 * rg + m;
        if (gr < NN) {
            __half2 h0 = __float22half2_rn(make_float2(acc[m][0], acc[m][1]));
            __half2 h1 = __float22half2_rn(make_float2(acc[m][2], acc[m][3]));
            __half2 h2 = __float22half2_rn(make_float2(acc[m][4], acc[m][5]));
            __half2 h3 = __float22half2_rn(make_float2(acc[m][6], acc[m][7]));
            uint4 p;
            p.x = *(const uint32_t*)&h0;
            p.y = *(const uint32_t*)&h1;
            p.z = *(const uint32_t*)&h2;
            p.w = *(const uint32_t*)&h3;
            *(uint4*)(Hh + (size_t)gr * 64 + jc * 4) = p;  // row stride 64 u32
        }
    }
}

// ---------------- aggregation ----------------
// One node per wave64, pair-split halves; lane loads uint2 = 4 fp16 features.
// 4B packed records prefetched one batch ahead.

static __device__ __forceinline__ void proc_edge(uint32_t rec, bool valid, int lh,
                                                 const uint2* __restrict__ hh2,
                                                 float4& acc) {
    const int s = (int)(rec & 0xffffu);
    unsigned short wb = (unsigned short)(rec >> 16);
    float w = valid ? __half2float(*(const __half*)&wb) : 0.0f;
    uint2 v = hh2[(size_t)s * 32 + lh];
    float2 lo = __half22float2(*(const __half2*)&v.x);
    float2 hi = __half22float2(*(const __half2*)&v.y);
    acc.x += w * lo.x;
    acc.y += w * lo.y;
    acc.z += w * hi.x;
    acc.w += w * hi.y;
}

__global__ __launch_bounds__(256) void agg_kernel(const uint2* __restrict__ hh2,
                                                  const int* __restrict__ offsets,
                                                  const uint32_t* __restrict__ csr,
                                                  const float* __restrict__ dinv,
                                                  const float* __restrict__ bias,
                                                  float* __restrict__ out,
                                                  const int relu) {
    const int node = blockIdx.x * 4 + (threadIdx.x >> 6);
    if (node >= NN) return;
    const int l = threadIdx.x & 63;
    const int half = l >> 5, lh = l & 31;
    const float di = dinv[node];
    const float sw = di * di;
    const int e0 = offsets[node];
    const int e1 = offsets[node + 1];

    float4 acc0 = make_float4(0.f, 0.f, 0.f, 0.f);
    float4 acc1 = make_float4(0.f, 0.f, 0.f, 0.f);
    float4 acc2 = make_float4(0.f, 0.f, 0.f, 0.f);
    float4 acc3 = make_float4(0.f, 0.f, 0.f, 0.f);

    if (e0 < e1) {
        const int elast = e1 - 1;
        uint32_t r0 = csr[min(e0 + 0 + half, elast)];
        uint32_t r1 = csr[min(e0 + 2 + half, elast)];
        uint32_t r2 = csr[min(e0 + 4 + half, elast)];
        uint32_t r3 = csr[min(e0 + 6 + half, elast)];
        for (int eb = e0; eb < e1; eb += 8) {
            const int nb = eb + 8;
            uint32_t n0 = csr[min(nb + 0 + half, elast)];
            uint32_t n1 = csr[min(nb + 2 + half, elast)];
            uint32_t n2 = csr[min(nb + 4 + half, elast)];
            uint32_t n3 = csr[min(nb + 6 + half, elast)];
            proc_edge(r0, eb + 0 + half < e1, lh, hh2, acc0);
            proc_edge(r1, eb + 2 + half < e1, lh, hh2, acc1);
            proc_edge(r2, eb + 4 + half < e1, lh, hh2, acc2);
            proc_edge(r3, eb + 6 + half < e1, lh, hh2, acc3);
            r0 = n0; r1 = n1; r2 = n2; r3 = n3;
        }
    }

    float4 s;
    s.x = (acc0.x + acc1.x) + (acc2.x + acc3.x);
    s.y = (acc0.y + acc1.y) + (acc2.y + acc3.y);
    s.z = (acc0.z + acc1.z) + (acc2.z + acc3.z);
    s.w = (acc0.w + acc1.w) + (acc2.w + acc3.w);
    s.x += __shfl_xor(s.x, 32, 64);
    s.y += __shfl_xor(s.y, 32, 64);
    s.z += __shfl_xor(s.z, 32, 64);
    s.w += __shfl_xor(s.w, 32, 64);

    // self term (fp16 copy) + bias
    uint2 sv = hh2[(size_t)node * 32 + lh];
    float2 slo = __half22float2(*(const __half2*)&sv.x);
    float2 shi = __half22float2(*(const __half2*)&sv.y);
    float4 bv = ((const float4*)bias)[lh];
    s.x += sw * slo.x + bv.x;
    s.y += sw * slo.y + bv.y;
    s.z += sw * shi.x + bv.z;
    s.w += sw * shi.y + bv.w;
    if (relu) {
        s.x = fmaxf(s.x, 0.f);
        s.y = fmaxf(s.y, 0.f);
        s.z = fmaxf(s.z, 0.f);
        s.w = fmaxf(s.w, 0.f);
    }
    if (half == 0) ((float4*)out)[(size_t)node * 32 + lh] = s;
}

// ---------------- launch ----------------

extern "C" void kernel_launch(void* const* d_in, const int* in_sizes, int n_in,
                              void* d_out, int out_size, void* d_ws, size_t ws_size,
                              hipStream_t stream) {
    (void)in_sizes; (void)n_in; (void)out_size; (void)ws_size;
    const float* x  = (const float*)d_in[0];
    const int*   ei = (const int*)d_in[1];
    const float* W1 = (const float*)d_in[2];
    const float* b1 = (const float*)d_in[3];
    const float* W2 = (const float*)d_in[4];
    const float* b2 = (const float*)d_in[5];
    const float* W3 = (const float*)d_in[6];
    const float* b3 = (const float*)d_in[7];
    const int* row = ei;
    const int* col = ei + NE;
    float* outp = (float*)d_out;

    char* ws = (char*)d_ws;
    size_t off = 0;
    auto walloc = [&](size_t bytes) -> void* {
        void* p = ws + off;
        off = (off + bytes + 255) & ~(size_t)255;
        return p;
    };
    int*      counts   = (int*)walloc(NN * 4 + 16);
    int*      excl     = (int*)walloc(NN * 4);
    int*      blocksums= (int*)walloc(NSB * 4);
    int*      blockoff = (int*)walloc(NSB * 4);
    int*      offsets  = (int*)walloc((NN + 1) * 4);
    int*      cursor   = (int*)walloc(NN * 4);
    float*    dinv     = (float*)walloc(NN * 4);
    uint32_t* csr      = (uint32_t*)walloc((size_t)NE * 4);
    float*    act      = (float*)walloc((size_t)NN * D * 4);
    uint32_t* hh16     = (uint32_t*)walloc((size_t)NN * D * 2);

    zero_kernel<<<(NN / 4 + 1 + 255) / 256, 256, 0, stream>>>((int4*)counts);
    count_kernel<<<(NE + 255) / 256, 256, 0, stream>>>(col, counts);
    scan1_kernel<<<NSB, 256, 0, stream>>>(counts, excl, blocksums);
    scan2_kernel<<<1, 64, 0, stream>>>(blocksums, blockoff);
    scan3_kernel<<<(NN + 255) / 256, 256, 0, stream>>>(counts, excl, blockoff,
                                                       offsets, cursor, dinv);
    fill_kernel<<<(NE + 255) / 256, 256, 0, stream>>>(row, col, dinv, cursor, csr);

    const int gblocks = (NN + 127) / 128;
    const int ablocks = (NN + 3) / 4;
    const uint2* hh2 = (const uint2*)hh16;
    // layer 1
    gemm_kernel<<<gblocks, 256, 0, stream>>>(x, W1, hh16);
    agg_kernel<<<ablocks, 256, 0, stream>>>(hh2, offsets, csr, dinv, b1, act, 1);
    // layer 2
    gemm_kernel<<<gblocks, 256, 0, stream>>>(act, W2, hh16);
    agg_kernel<<<ablocks, 256, 0, stream>>>(hh2, offsets, csr, dinv, b2, act, 1);
    // layer 3 (no relu)
    gemm_kernel<<<gblocks, 256, 0, stream>>>(act, W3, hh16);
    agg_kernel<<<ablocks, 256, 0, stream>>>(hh2, offsets, csr, dinv, b3, outp, 0);
}

// Round 8
// 215.775 us; speedup vs baseline: 1.9829x; 1.1395x over previous
//
#include <hip/hip_runtime.h>
#include <hip/hip_fp16.h>

#define NN 50000
#define NE 625000
#define D 128
#define SCAN_BLK 1024  // elements per scan1 block
#define NSB ((NN + SCAN_BLK - 1) / SCAN_BLK)  // 49

typedef _Float16 half8 __attribute__((ext_vector_type(8)));
typedef float f32x4 __attribute__((ext_vector_type(4)));

union H8U4 { _Float16 h[8]; uint4 u; };

// ---------------- CSR build ----------------

__global__ void zero_kernel(int4* __restrict__ p) {
    int i = blockIdx.x * blockDim.x + threadIdx.x;
    if (i < NN / 4 + 1) p[i] = make_int4(0, 0, 0, 0);
}

__global__ void count_kernel(const int* __restrict__ col, int* __restrict__ counts) {
    int i = blockIdx.x * blockDim.x + threadIdx.x;
    if (i < NE) atomicAdd(&counts[col[i]], 1);
}

__global__ __launch_bounds__(256) void scan1_kernel(const int* __restrict__ counts,
                                                    int* __restrict__ excl,
                                                    int* __restrict__ blocksums) {
    const int b = blockIdx.x, t = threadIdx.x;
    const int base = b * SCAN_BLK + t * 4;
    int v0 = 0, v1 = 0, v2 = 0, v3 = 0;
    if (base + 3 < NN) {
        int4 c = *(const int4*)(counts + base);
        v0 = c.x; v1 = c.y; v2 = c.z; v3 = c.w;
    } else {
        if (base     < NN) v0 = counts[base];
        if (base + 1 < NN) v1 = counts[base + 1];
        if (base + 2 < NN) v2 = counts[base + 2];
        if (base + 3 < NN) v3 = counts[base + 3];
    }
    const int s = v0 + v1 + v2 + v3;
    const int lane = t & 63, wid = t >> 6;
    int inc = s;
    #pragma unroll
    for (int off = 1; off < 64; off <<= 1) {
        int n = __shfl_up(inc, off, 64);
        if (lane >= off) inc += n;
    }
    __shared__ int wsum[4];
    if (lane == 63) wsum[wid] = inc;
    __syncthreads();
    int wbase = 0;
    for (int w = 0; w < wid; w++) wbase += wsum[w];
    const int texcl = wbase + inc - s;
    if (base     < NN) excl[base]     = texcl;
    if (base + 1 < NN) excl[base + 1] = texcl + v0;
    if (base + 2 < NN) excl[base + 2] = texcl + v0 + v1;
    if (base + 3 < NN) excl[base + 3] = texcl + v0 + v1 + v2;
    if (t == 255) blocksums[b] = wbase + inc;
}

__global__ __launch_bounds__(64) void scan2_kernel(const int* __restrict__ blocksums,
                                                   int* __restrict__ blockoff) {
    const int t = threadIdx.x;
    int v = (t < NSB) ? blocksums[t] : 0;
    int inc = v;
    #pragma unroll
    for (int off = 1; off < 64; off <<= 1) {
        int n = __shfl_up(inc, off, 64);
        if (t >= off) inc += n;
    }
    if (t < NSB) blockoff[t] = inc - v;
}

__global__ void scan3_kernel(const int* __restrict__ counts, const int* __restrict__ excl,
                             const int* __restrict__ blockoff, int* __restrict__ offsets,
                             int* __restrict__ cursor, float* __restrict__ dinv) {
    const int i = blockIdx.x * blockDim.x + threadIdx.x;
    if (i < NN) {
        const int o = excl[i] + blockoff[i >> 10];
        offsets[i] = o;
        cursor[i] = o;
        dinv[i] = rsqrtf((float)counts[i] + 1.0f);
    }
    if (i == 0) offsets[NN] = NE;
}

// Packed 4B edge record: lo16 = src index (NN<65536), hi16 = fp16 weight.
__global__ void fill_kernel(const int* __restrict__ row, const int* __restrict__ col,
                            const float* __restrict__ dinv, int* __restrict__ cursor,
                            uint32_t* __restrict__ csr) {
    int i = blockIdx.x * blockDim.x + threadIdx.x;
    if (i < NE) {
        int r = row[i], c = col[i];
        int p = atomicAdd(&cursor[c], 1);
        __half hw = __float2half_rn(dinv[r] * dinv[c]);
        csr[p] = (uint32_t)r | ((uint32_t)*(const unsigned short*)&hw << 16);
    }
}

// ---------------- W pre-pack into MFMA B-fragment order ----------------
// wp[(ks*8+ctg)*64 + lane] = 8 f16 of W[k][j], k = ks*32+(lane>>4)*8+e,
// j = ctg*16+(lane&15). Same k-labeling as the A fragments.

__global__ __launch_bounds__(256) void wpack_kernel(const float* __restrict__ W,
                                                    uint4* __restrict__ wp) {
    int t = blockIdx.x * blockDim.x + threadIdx.x;
    if (t >= 2048) return;
    int lane = t & 63, entry = t >> 6;
    int ks = entry >> 3, ctg = entry & 7;
    int j = ctg * 16 + (lane & 15);
    int kb = ks * 32 + (lane >> 4) * 8;
    H8U4 u;
    #pragma unroll
    for (int e = 0; e < 8; e++) u.h[e] = (_Float16)W[(kb + e) * 128 + j];
    wp[t] = u.u;
}

// ---------------- MFMA GEMM: Hh(fp16) = A @ W ----------------
// 64 rows x 128 cols per 256-thread block (4 waves; wave w owns cols w*32..).
// mfma_f32_16x16x32_f16, fp32 accumulate; epilogue via padded LDS.

template <bool IN_F16>
__global__ __launch_bounds__(256) void gemm_mfma(const void* __restrict__ Ain,
                                                 const uint4* __restrict__ wpack,
                                                 uint32_t* __restrict__ Hh) {
    __shared__ alignas(16) _Float16 Cs[64][152];  // row stride 304B = 19*16 ✓
    const int t = threadIdx.x;
    const int w = t >> 6, l = t & 63;
    const int row0 = blockIdx.x * 64;
    const int lr = l & 15;   // M/N lane index within a 16x16 tile
    const int lg = l >> 4;   // k-group

    int arow[4];
    #pragma unroll
    for (int rt = 0; rt < 4; rt++) {
        int gr = row0 + rt * 16 + lr;
        arow[rt] = (gr < NN) ? gr : NN - 1;
    }

    f32x4 acc[4][2];
    #pragma unroll
    for (int rt = 0; rt < 4; rt++)
        #pragma unroll
        for (int ct = 0; ct < 2; ct++)
            acc[rt][ct] = (f32x4){0.f, 0.f, 0.f, 0.f};

    #pragma unroll
    for (int ks = 0; ks < 4; ks++) {
        const int kbase = ks * 32 + lg * 8;
        half8 af[4];
        if (IN_F16) {
            const uint4* A = (const uint4*)Ain;  // fp16 row = 16 uint4
            #pragma unroll
            for (int rt = 0; rt < 4; rt++) {
                H8U4 u;
                u.u = A[arow[rt] * 16 + (kbase >> 3)];
                af[rt] = *(half8*)u.h;
            }
        } else {
            const float4* A = (const float4*)Ain;  // fp32 row = 32 float4
            #pragma unroll
            for (int rt = 0; rt < 4; rt++) {
                float4 p0 = A[arow[rt] * 32 + (kbase >> 2)];
                float4 p1 = A[arow[rt] * 32 + (kbase >> 2) + 1];
                half8 h;
                h[0] = (_Float16)p0.x; h[1] = (_Float16)p0.y;
                h[2] = (_Float16)p0.z; h[3] = (_Float16)p0.w;
                h[4] = (_Float16)p1.x; h[5] = (_Float16)p1.y;
                h[6] = (_Float16)p1.z; h[7] = (_Float16)p1.w;
                af[rt] = h;
            }
        }
        half8 bf[2];
        #pragma unroll
        for (int ct = 0; ct < 2; ct++) {
            H8U4 u;
            u.u = wpack[(ks * 8 + (w * 2 + ct)) * 64 + l];
            bf[ct] = *(half8*)u.h;
        }
        #pragma unroll
        for (int rt = 0; rt < 4; rt++)
            #pragma unroll
            for (int ct = 0; ct < 2; ct++)
                acc[rt][ct] = __builtin_amdgcn_mfma_f32_16x16x32_f16(
                    af[rt], bf[ct], acc[rt][ct], 0, 0, 0);
    }

    // stage C to LDS as fp16 (C/D: col = lane&15, row = (lane>>4)*4 + reg)
    #pragma unroll
    for (int rt = 0; rt < 4; rt++)
        #pragma unroll
        for (int ct = 0; ct < 2; ct++) {
            const int col = w * 32 + ct * 16 + lr;
            #pragma unroll
            for (int r = 0; r < 4; r++)
                Cs[rt * 16 + lg * 4 + r][col] = (_Float16)acc[rt][ct][r];
        }
    __syncthreads();

    #pragma unroll
    for (int i = t; i < 1024; i += 256) {
        const int row = i >> 4, c16 = i & 15;
        if (row0 + row < NN) {
            uint4 u = *(const uint4*)&Cs[row][c16 * 8];
            *(uint4*)(Hh + (size_t)(row0 + row) * 64 + c16 * 4) = u;
        }
    }
}

// ---------------- aggregation ----------------
// One node per wave64, pair-split halves; lane loads uint2 = 4 fp16 features.
// 4B packed records prefetched one batch ahead. OUT_F16: packed fp16 act.

static __device__ __forceinline__ void proc_edge(uint32_t rec, bool valid, int lh,
                                                 const uint2* __restrict__ hh2,
                                                 float4& acc) {
    const int s = (int)(rec & 0xffffu);
    unsigned short wb = (unsigned short)(rec >> 16);
    float w = valid ? __half2float(*(const __half*)&wb) : 0.0f;
    uint2 v = hh2[(size_t)s * 32 + lh];
    float2 lo = __half22float2(*(const __half2*)&v.x);
    float2 hi = __half22float2(*(const __half2*)&v.y);
    acc.x += w * lo.x;
    acc.y += w * lo.y;
    acc.z += w * hi.x;
    acc.w += w * hi.y;
}

template <bool OUT_F16>
__global__ __launch_bounds__(256) void agg_kernel(const uint2* __restrict__ hh2,
                                                  const int* __restrict__ offsets,
                                                  const uint32_t* __restrict__ csr,
                                                  const float* __restrict__ dinv,
                                                  const float* __restrict__ bias,
                                                  void* __restrict__ out,
                                                  const int relu) {
    const int node = blockIdx.x * 4 + (threadIdx.x >> 6);
    if (node >= NN) return;
    const int l = threadIdx.x & 63;
    const int half = l >> 5, lh = l & 31;
    const float di = dinv[node];
    const float sw = di * di;
    const int e0 = offsets[node];
    const int e1 = offsets[node + 1];

    float4 acc0 = make_float4(0.f, 0.f, 0.f, 0.f);
    float4 acc1 = make_float4(0.f, 0.f, 0.f, 0.f);
    float4 acc2 = make_float4(0.f, 0.f, 0.f, 0.f);
    float4 acc3 = make_float4(0.f, 0.f, 0.f, 0.f);

    if (e0 < e1) {
        const int elast = e1 - 1;
        uint32_t r0 = csr[min(e0 + 0 + half, elast)];
        uint32_t r1 = csr[min(e0 + 2 + half, elast)];
        uint32_t r2 = csr[min(e0 + 4 + half, elast)];
        uint32_t r3 = csr[min(e0 + 6 + half, elast)];
        for (int eb = e0; eb < e1; eb += 8) {
            const int nb = eb + 8;
            uint32_t n0 = csr[min(nb + 0 + half, elast)];
            uint32_t n1 = csr[min(nb + 2 + half, elast)];
            uint32_t n2 = csr[min(nb + 4 + half, elast)];
            uint32_t n3 = csr[min(nb + 6 + half, elast)];
            proc_edge(r0, eb + 0 + half < e1, lh, hh2, acc0);
            proc_edge(r1, eb + 2 + half < e1, lh, hh2, acc1);
            proc_edge(r2, eb + 4 + half < e1, lh, hh2, acc2);
            proc_edge(r3, eb + 6 + half < e1, lh, hh2, acc3);
            r0 = n0; r1 = n1; r2 = n2; r3 = n3;
        }
    }

    float4 s;
    s.x = (acc0.x + acc1.x) + (acc2.x + acc3.x);
    s.y = (acc0.y + acc1.y) + (acc2.y + acc3.y);
    s.z = (acc0.z + acc1.z) + (acc2.z + acc3.z);
    s.w = (acc0.w + acc1.w) + (acc2.w + acc3.w);
    s.x += __shfl_xor(s.x, 32, 64);
    s.y += __shfl_xor(s.y, 32, 64);
    s.z += __shfl_xor(s.z, 32, 64);
    s.w += __shfl_xor(s.w, 32, 64);

    // self term (fp16 copy) + bias
    uint2 sv = hh2[(size_t)node * 32 + lh];
    float2 slo = __half22float2(*(const __half2*)&sv.x);
    float2 shi = __half22float2(*(const __half2*)&sv.y);
    float4 bv = ((const float4*)bias)[lh];
    s.x += sw * slo.x + bv.x;
    s.y += sw * slo.y + bv.y;
    s.z += sw * shi.x + bv.z;
    s.w += sw * shi.y + bv.w;
    if (relu) {
        s.x = fmaxf(s.x, 0.f);
        s.y = fmaxf(s.y, 0.f);
        s.z = fmaxf(s.z, 0.f);
        s.w = fmaxf(s.w, 0.f);
    }
    if (half == 0) {
        if (OUT_F16) {
            __half2 p0 = __float22half2_rn(make_float2(s.x, s.y));
            __half2 p1 = __float22half2_rn(make_float2(s.z, s.w));
            uint2 u = make_uint2(*(const uint32_t*)&p0, *(const uint32_t*)&p1);
            *(uint2*)((uint32_t*)out + (size_t)node * 64 + lh * 2) = u;
        } else {
            ((float4*)out)[(size_t)node * 32 + lh] = s;
        }
    }
}

// ---------------- launch ----------------

extern "C" void kernel_launch(void* const* d_in, const int* in_sizes, int n_in,
                              void* d_out, int out_size, void* d_ws, size_t ws_size,
                              hipStream_t stream) {
    (void)in_sizes; (void)n_in; (void)out_size; (void)ws_size;
    const float* x  = (const float*)d_in[0];
    const int*   ei = (const int*)d_in[1];
    const float* W1 = (const float*)d_in[2];
    const float* b1 = (const float*)d_in[3];
    const float* W2 = (const float*)d_in[4];
    const float* b2 = (const float*)d_in[5];
    const float* W3 = (const float*)d_in[6];
    const float* b3 = (const float*)d_in[7];
    const int* row = ei;
    const int* col = ei + NE;
    float* outp = (float*)d_out;

    char* ws = (char*)d_ws;
    size_t off = 0;
    auto walloc = [&](size_t bytes) -> void* {
        void* p = ws + off;
        off = (off + bytes + 255) & ~(size_t)255;
        return p;
    };
    int*      counts   = (int*)walloc(NN * 4 + 16);
    int*      excl     = (int*)walloc(NN * 4);
    int*      blocksums= (int*)walloc(NSB * 4);
    int*      blockoff = (int*)walloc(NSB * 4);
    int*      offsets  = (int*)walloc((NN + 1) * 4);
    int*      cursor   = (int*)walloc(NN * 4);
    float*    dinv     = (float*)walloc(NN * 4);
    uint32_t* csr      = (uint32_t*)walloc((size_t)NE * 4);
    uint32_t* act16    = (uint32_t*)walloc((size_t)NN * D * 2);
    uint32_t* hh16     = (uint32_t*)walloc((size_t)NN * D * 2);
    uint4*    wp1      = (uint4*)walloc(2048 * 16);
    uint4*    wp2      = (uint4*)walloc(2048 * 16);
    uint4*    wp3      = (uint4*)walloc(2048 * 16);

    zero_kernel<<<(NN / 4 + 1 + 255) / 256, 256, 0, stream>>>((int4*)counts);
    count_kernel<<<(NE + 255) / 256, 256, 0, stream>>>(col, counts);
    scan1_kernel<<<NSB, 256, 0, stream>>>(counts, excl, blocksums);
    scan2_kernel<<<1, 64, 0, stream>>>(blocksums, blockoff);
    scan3_kernel<<<(NN + 255) / 256, 256, 0, stream>>>(counts, excl, blockoff,
                                                       offsets, cursor, dinv);
    fill_kernel<<<(NE + 255) / 256, 256, 0, stream>>>(row, col, dinv, cursor, csr);
    wpack_kernel<<<8, 256, 0, stream>>>(W1, wp1);
    wpack_kernel<<<8, 256, 0, stream>>>(W2, wp2);
    wpack_kernel<<<8, 256, 0, stream>>>(W3, wp3);

    const int gblocks = (NN + 63) / 64;
    const int ablocks = (NN + 3) / 4;
    const uint2* hh2 = (const uint2*)hh16;
    // layer 1
    gemm_mfma<false><<<gblocks, 256, 0, stream>>>(x, wp1, hh16);
    agg_kernel<true><<<ablocks, 256, 0, stream>>>(hh2, offsets, csr, dinv, b1, act16, 1);
    // layer 2
    gemm_mfma<true><<<gblocks, 256, 0, stream>>>(act16, wp2, hh16);
    agg_kernel<true><<<ablocks, 256, 0, stream>>>(hh2, offsets, csr, dinv, b2, act16, 1);
    // layer 3 (no relu, fp32 out)
    gemm_mfma<true><<<gblocks, 256, 0, stream>>>(act16, wp3, hh16);
    agg_kernel<false><<<ablocks, 256, 0, stream>>>(hh2, offsets, csr, dinv, b3, outp, 0);
}